// Round 1
// baseline (282.933 us; speedup 1.0000x reference)
//
#include <hip/hip_runtime.h>
#include <stdint.h>

#define GLOBAL_AS __attribute__((address_space(1)))
#define LDS_AS    __attribute__((address_space(3)))

typedef int v4i __attribute__((ext_vector_type(4)));

__device__ __forceinline__ void gload_lds16(const void* g, void* l) {
    __builtin_amdgcn_global_load_lds((GLOBAL_AS uint32_t*)g, (LDS_AS uint32_t*)l, 16, 0, 0);
}

// ---------------- kernel 1: max |tanh(w)| over all 3*3*256*256 weights ----------------
__global__ void k_wmax(const float* __restrict__ w, unsigned* __restrict__ maxbits, int n) {
    int i = blockIdx.x * blockDim.x + threadIdx.x;
    int stride = gridDim.x * blockDim.x;
    float m = 0.f;
    for (; i < n; i += stride) m = fmaxf(m, fabsf(tanhf(w[i])));
#pragma unroll
    for (int off = 32; off > 0; off >>= 1)
        m = fmaxf(m, __shfl_xor(m, off, 64));
    if ((threadIdx.x & 63) == 0) atomicMax(maxbits, __float_as_uint(m));
}

// ---------------- kernel 2: quantize weights -> int8 {-3,-1,1,3}, layout [co][tap*256+ci] ----
__global__ void k_wq(const float* __restrict__ w, const unsigned* __restrict__ maxbits,
                     int8_t* __restrict__ wqt) {
    int t = blockIdx.x * 256 + threadIdx.x;   // 0 .. 589824, co-major
    int co = t / 2304;
    int k  = t - co * 2304;                   // tap*256 + ci
    float ma = __uint_as_float(*maxbits);
    float tv = tanhf(w[(long)k * 256 + co]);  // HWIO: [k][co]
    float tq = tv / ma * 0.5f + 0.5f;         // in [0,1]
    int qi = (int)rintf(tq * 3.0f);           // 0..3, round-half-even matches jnp.round
    wqt[t] = (int8_t)(2 * qi - 3);            // {-3,-1,1,3} = 3 * (2*q/3 - 1)
}

// ---------------- kernel 3: quantize acts -> int8 {0..3} into zero-padded [32][58][58][256] ---
__global__ void k_xq(const float* __restrict__ x, int8_t* __restrict__ xqp) {
    int t = blockIdx.x * 256 + threadIdx.x;   // 32*58*58*16 threads, 16 bytes each
    int g  = t & 15;
    int p  = t >> 4;
    int xp = p % 58;
    int q  = p / 58;
    int yp = q % 58;
    int n  = q / 58;
    int4 r;
    if (yp == 0 || yp == 57 || xp == 0 || xp == 57) {
        r = make_int4(0, 0, 0, 0);
    } else {
        const float4* px = (const float4*)(x + (((long)((n * 56 + (yp - 1)) * 56 + (xp - 1))) << 8) + g * 16);
        int wds[4];
#pragma unroll
        for (int jj = 0; jj < 4; ++jj) {
            float4 v = px[jj];
            int b0 = (int)rintf(fminf(fmaxf(v.x, 0.f), 1.f) * 3.f);
            int b1 = (int)rintf(fminf(fmaxf(v.y, 0.f), 1.f) * 3.f);
            int b2 = (int)rintf(fminf(fmaxf(v.z, 0.f), 1.f) * 3.f);
            int b3 = (int)rintf(fminf(fmaxf(v.w, 0.f), 1.f) * 3.f);
            wds[jj] = b0 | (b1 << 8) | (b2 << 16) | (b3 << 24);
        }
        r = make_int4(wds[0], wds[1], wds[2], wds[3]);
    }
    *(int4*)(xqp + ((long)t << 4)) = r;
}

// ---------------- kernel 4: implicit-GEMM conv, i8 MFMA -------------------------------------
// C[M=100352][256] = A[M][2304] * B[2304][256], A = padded xq (implicit im2col), B = wq.
// BM=BN=128, BK=64. 4 waves, each 64x64 via 4x4 mfma_i32_16x16x64_i8. out = acc/9.
#define BM 128
#define BN 128

__global__ __launch_bounds__(256) void k_conv(const int8_t* __restrict__ xqp,
                                              const int8_t* __restrict__ wqt,
                                              float* __restrict__ out) {
    __shared__ int8_t sA[BM * 64];   // 8 KB: [row 0..127][64 bytes of K-chunk]
    __shared__ int8_t sB[BN * 64];   // 8 KB: [co-local 0..127][64 bytes of K-chunk]

    const int tid    = threadIdx.x;
    const int wv     = tid >> 6;
    const int lane   = tid & 63;
    const int mBase  = blockIdx.x * BM;
    const int coBase = blockIdx.y * BN;

    // per-lane loop-invariant staging bases: lane -> (row = lq, 16B chunk = lb)
    const int lq = lane >> 2;
    const int lb = (lane & 3) * 16;
    const int8_t* aPtr[2];
    const int8_t* bPtr[2];
#pragma unroll
    for (int j = 0; j < 2; ++j) {
        int i = wv * 32 + j * 16 + lq;         // tile row this lane stages
        int m = mBase + i;
        int n = m / 3136;
        int r = m - n * 3136;
        int y = r / 56;
        int x = r - y * 56;
        // padded coords: center tap (ky=kx=0 offset) starts at (y, x) in the 58x58 buffer
        aPtr[j] = xqp + (((long)((n * 58 + y) * 58 + x)) << 8) + lb;
        int cl = coBase + wv * 32 + j * 16 + lq;
        bPtr[j] = wqt + (long)cl * 2304 + lb;
    }
    int8_t* sAw = sA + (wv * 32) * 64;   // wave-uniform LDS dests (1 KB per instruction)
    int8_t* sBw = sB + (wv * 32) * 64;

    v4i acc[4][4];
#pragma unroll
    for (int a = 0; a < 4; ++a)
#pragma unroll
        for (int b = 0; b < 4; ++b) acc[a][b] = (v4i){0, 0, 0, 0};

    const int wm   = (wv & 1) * 64;
    const int wn   = (wv >> 1) * 64;
    const int frow = lane & 15;
    const int fq16 = (lane >> 4) * 16;

    for (int tap = 0; tap < 9; ++tap) {
        const int ky = tap / 3;
        const int kx = tap - ky * 3;
        const int aoffTap = ((ky * 58) + kx) << 8;   // byte offset in padded xq
        const int boffTap = tap << 8;                // byte offset in wqt row
#pragma unroll
        for (int cc = 0; cc < 4; ++cc) {
            __syncthreads();                          // previous compute done before overwrite
            const int ao = aoffTap + cc * 64;
            const int bo = boffTap + cc * 64;
            gload_lds16(aPtr[0] + ao, sAw);
            gload_lds16(aPtr[1] + ao, sAw + 1024);
            gload_lds16(bPtr[0] + bo, sBw);
            gload_lds16(bPtr[1] + bo, sBw + 1024);
            __syncthreads();                          // staging visible (compiler drains vmcnt)

            v4i af[4], bf[4];
#pragma unroll
            for (int mt = 0; mt < 4; ++mt)
                af[mt] = *(const v4i*)(sA + (wm + mt * 16 + frow) * 64 + fq16);
#pragma unroll
            for (int nt = 0; nt < 4; ++nt)
                bf[nt] = *(const v4i*)(sB + (wn + nt * 16 + frow) * 64 + fq16);
#pragma unroll
            for (int mt = 0; mt < 4; ++mt)
#pragma unroll
                for (int nt = 0; nt < 4; ++nt)
                    acc[mt][nt] = __builtin_amdgcn_mfma_i32_16x16x64_i8(af[mt], bf[nt], acc[mt][nt], 0, 0, 0);
        }
    }

    // epilogue: C/D layout col=lane&15, row=(lane>>4)*4+reg; out = acc/9
    const float s = 1.0f / 9.0f;
    const int colB  = coBase + wn + frow;
    const int rquad = (lane >> 4) * 4;
#pragma unroll
    for (int mt = 0; mt < 4; ++mt) {
#pragma unroll
        for (int nt = 0; nt < 4; ++nt) {
            const int col = colB + nt * 16;
            const long mrow = mBase + wm + mt * 16 + rquad;
#pragma unroll
            for (int r = 0; r < 4; ++r)
                out[(mrow + r) * 256 + col] = (float)acc[mt][nt][r] * s;
        }
    }
}

extern "C" void kernel_launch(void* const* d_in, const int* in_sizes, int n_in,
                              void* d_out, int out_size, void* d_ws, size_t ws_size,
                              hipStream_t stream) {
    const float* x = (const float*)d_in[0];   // (32,56,56,256) NHWC fp32
    const float* w = (const float*)d_in[1];   // (3,3,256,256) HWIO fp32
    float* out = (float*)d_out;               // (32,56,56,256) fp32

    unsigned* maxbits = (unsigned*)d_ws;
    int8_t* wqt = (int8_t*)d_ws + 4096;              // 2304*256 = 589824 B, [co][k]
    int8_t* xqp = (int8_t*)d_ws + 4096 + 589824;     // 32*58*58*256 = 27,557,888 B

    hipMemsetAsync(maxbits, 0, 4, stream);           // ws is poisoned 0xAA -> must zero for atomicMax
    k_wmax<<<256, 256, 0, stream>>>(w, maxbits, 3 * 3 * 256 * 256);
    k_wq<<<2304, 256, 0, stream>>>(w, maxbits, wqt);
    k_xq<<<6728, 256, 0, stream>>>(x, xqp);          // 32*58*58*16 threads
    dim3 grid(784, 2);                               // 100352/128 x 256/128
    k_conv<<<grid, 256, 0, stream>>>(xqp, wqt, out);
}

// Round 2
// 275.676 us; speedup vs baseline: 1.0263x; 1.0263x over previous
//
#include <hip/hip_runtime.h>
#include <stdint.h>

#define GLOBAL_AS __attribute__((address_space(1)))
#define LDS_AS    __attribute__((address_space(3)))

typedef int v4i  __attribute__((ext_vector_type(4)));
typedef int v16i __attribute__((ext_vector_type(16)));

__device__ __forceinline__ void gload_lds16(const void* g, void* l) {
    __builtin_amdgcn_global_load_lds((GLOBAL_AS uint32_t*)g, (LDS_AS uint32_t*)l, 16, 0, 0);
}

// ---------------- kernel 1: max |tanh(w)| over all 3*3*256*256 weights ----------------
__global__ void k_wmax(const float* __restrict__ w, unsigned* __restrict__ maxbits, int n) {
    int i = blockIdx.x * blockDim.x + threadIdx.x;
    int stride = gridDim.x * blockDim.x;
    float m = 0.f;
    for (; i < n; i += stride) m = fmaxf(m, fabsf(tanhf(w[i])));
#pragma unroll
    for (int off = 32; off > 0; off >>= 1)
        m = fmaxf(m, __shfl_xor(m, off, 64));
    if ((threadIdx.x & 63) == 0) atomicMax(maxbits, __float_as_uint(m));
}

// ---------------- kernel 2: quantize weights -> int8 {-3,-1,1,3}, layout [co][tap*256+ci] ----
// coalesced reads (co along lanes), 16B packed writes
__global__ void k_wq(const float* __restrict__ w, const unsigned* __restrict__ maxbits,
                     int8_t* __restrict__ wqt) {
    int t = blockIdx.x * 256 + threadIdx.x;   // 36864 threads
    int co = t & 255;
    int kblk = t >> 8;                        // 0..143, 16 k-values each
    float inv = 0.5f / __uint_as_float(*maxbits);
    int8_t b[16];
#pragma unroll
    for (int i = 0; i < 16; ++i) {
        float tv = tanhf(w[(long)(kblk * 16 + i) * 256 + co]);   // HWIO [k][co]
        int qi = (int)rintf((tv * inv + 0.5f) * 3.0f);           // 0..3, half-even = jnp.round
        b[i] = (int8_t)(2 * qi - 3);                             // {-3,-1,1,3}
    }
    *(int4*)(wqt + (long)co * 2304 + kblk * 16) = *(int4*)b;
}

// ---------------- kernel 3: quantize acts -> int8 {0..3} into zero-padded [32][58][58][256] ---
__global__ void k_xq(const float* __restrict__ x, int8_t* __restrict__ xqp) {
    int t = blockIdx.x * 256 + threadIdx.x;   // 32*58*58*16 threads, 16 bytes each
    int g  = t & 15;
    int p  = t >> 4;
    int xp = p % 58;
    int q  = p / 58;
    int yp = q % 58;
    int n  = q / 58;
    int4 r;
    if (yp == 0 || yp == 57 || xp == 0 || xp == 57) {
        r = make_int4(0, 0, 0, 0);
    } else {
        const float4* px = (const float4*)(x + (((long)((n * 56 + (yp - 1)) * 56 + (xp - 1))) << 8) + g * 16);
        int wds[4];
#pragma unroll
        for (int jj = 0; jj < 4; ++jj) {
            float4 v = px[jj];
            int b0 = (int)rintf(fminf(fmaxf(v.x, 0.f), 1.f) * 3.f);
            int b1 = (int)rintf(fminf(fmaxf(v.y, 0.f), 1.f) * 3.f);
            int b2 = (int)rintf(fminf(fmaxf(v.z, 0.f), 1.f) * 3.f);
            int b3 = (int)rintf(fminf(fmaxf(v.w, 0.f), 1.f) * 3.f);
            wds[jj] = b0 | (b1 << 8) | (b2 << 16) | (b3 << 24);
        }
        r = make_int4(wds[0], wds[1], wds[2], wds[3]);
    }
    *(int4*)(xqp + ((long)t << 4)) = r;
}

// ---------------- kernel 4: implicit-GEMM conv, i8 MFMA 32x32x32 ----------------------------
// C[100352][256] = A[M][2304] * B[2304][256]; BM=BN=128, BK=128B (half tap), 18 K-iters.
// LDS layout [row][128B] with XOR chunk swizzle: physical 16B-chunk p holds global chunk
// p ^ (row&7)  -> conflict-free b128 fragment reads, and staging stays lane-contiguous
// for global_load_lds (wave-uniform base + lane*16).
#define BM 128
#define BN 128

__global__ __launch_bounds__(256) void k_conv(const int8_t* __restrict__ xqp,
                                              const int8_t* __restrict__ wqt,
                                              float* __restrict__ out) {
    __shared__ int8_t sA[BM * 128];   // 16 KB
    __shared__ int8_t sB[BN * 128];   // 16 KB

    const int tid    = threadIdx.x;
    const int wv     = tid >> 6;
    const int lane   = tid & 63;
    const int mBase  = blockIdx.x * BM;
    const int coBase = blockIdx.y * BN;

    // staging: instruction (wv, j) covers tile rows rbase..rbase+7, rbase = wv*8 + j*32
    // lane -> row = rbase + (lane>>3), phys chunk p = lane&7, global chunk g = p ^ (row&7)
    const int lr = lane >> 3;
    const int lp = lane & 7;
    const int8_t* aB[4];
    const int8_t* bB[4];
#pragma unroll
    for (int j = 0; j < 4; ++j) {
        int r = wv * 8 + j * 32 + lr;
        int g = lp ^ (r & 7);
        int m = mBase + r;
        int n = m / 3136;
        int rem = m - n * 3136;
        int y = rem / 56;
        int x = rem - y * 56;
        aB[j] = xqp + (((long)((n * 58 + y) * 58 + x)) << 8) + g * 16;
        bB[j] = wqt + (long)(coBase + r) * 2304 + g * 16;
    }

    v16i acc[2][2];
#pragma unroll
    for (int a = 0; a < 2; ++a)
#pragma unroll
        for (int b = 0; b < 2; ++b)
#pragma unroll
            for (int r = 0; r < 16; ++r) acc[a][b][r] = 0;

    const int wm  = (wv & 1) * 64;
    const int wn  = (wv >> 1) * 64;
    const int l31 = lane & 31;
    const int hi  = lane >> 5;

    // fragment bases + per-row XOR terms
    const int rA0 = wm + l31,      rA1 = wm + 32 + l31;
    const int rB0 = wn + l31,      rB1 = wn + 32 + l31;
    const int8_t* aF0 = sA + rA0 * 128;  const int axr0 = (rA0 & 7) << 4;
    const int8_t* aF1 = sA + rA1 * 128;  const int axr1 = (rA1 & 7) << 4;
    const int8_t* bF0 = sB + rB0 * 128;  const int bxr0 = (rB0 & 7) << 4;
    const int8_t* bF1 = sB + rB1 * 128;  const int bxr1 = (rB1 & 7) << 4;

    for (int iter = 0; iter < 18; ++iter) {
        const int tap  = iter >> 1;
        const int ky   = tap / 3;
        const int kx   = tap - ky * 3;
        const int half = (iter & 1) * 128;
        const int aOff = (((ky * 58) + kx) << 8) + half;   // spatial shift + ci offset
        const int bOff = tap * 256 + half;

        __syncthreads();   // previous compute done before overwrite
#pragma unroll
        for (int j = 0; j < 4; ++j) {
            gload_lds16(aB[j] + aOff, sA + (wv * 8 + j * 32) * 128);
            gload_lds16(bB[j] + bOff, sB + (wv * 8 + j * 32) * 128);
        }
        __syncthreads();   // staging visible (compiler drains vmcnt)

#pragma unroll
        for (int kk = 0; kk < 4; ++kk) {
            const int kc = (kk * 2 + hi) << 4;   // K-chunk byte offset (16B granules)
            v4i a0 = *(const v4i*)(aF0 + (kc ^ axr0));
            v4i a1 = *(const v4i*)(aF1 + (kc ^ axr1));
            v4i b0 = *(const v4i*)(bF0 + (kc ^ bxr0));
            v4i b1 = *(const v4i*)(bF1 + (kc ^ bxr1));
            acc[0][0] = __builtin_amdgcn_mfma_i32_32x32x32_i8(a0, b0, acc[0][0], 0, 0, 0);
            acc[0][1] = __builtin_amdgcn_mfma_i32_32x32x32_i8(a0, b1, acc[0][1], 0, 0, 0);
            acc[1][0] = __builtin_amdgcn_mfma_i32_32x32x32_i8(a1, b0, acc[1][0], 0, 0, 0);
            acc[1][1] = __builtin_amdgcn_mfma_i32_32x32x32_i8(a1, b1, acc[1][1], 0, 0, 0);
        }
    }

    // epilogue: 32x32 C/D layout col=lane&31, row=(reg&3)+8*(reg>>2)+4*(lane>>5); out = acc/9
    const float s = 1.0f / 9.0f;
#pragma unroll
    for (int mt = 0; mt < 2; ++mt) {
#pragma unroll
        for (int nt = 0; nt < 2; ++nt) {
            const int ocol = coBase + wn + nt * 32 + l31;
#pragma unroll
            for (int reg = 0; reg < 16; ++reg) {
                const int row = (reg & 3) + 8 * (reg >> 2) + 4 * hi;
                const long orow = mBase + wm + mt * 32 + row;
                out[orow * 256 + ocol] = (float)acc[mt][nt][reg] * s;
            }
        }
    }
}

extern "C" void kernel_launch(void* const* d_in, const int* in_sizes, int n_in,
                              void* d_out, int out_size, void* d_ws, size_t ws_size,
                              hipStream_t stream) {
    const float* x = (const float*)d_in[0];   // (32,56,56,256) NHWC fp32
    const float* w = (const float*)d_in[1];   // (3,3,256,256) HWIO fp32
    float* out = (float*)d_out;               // (32,56,56,256) fp32

    unsigned* maxbits = (unsigned*)d_ws;
    int8_t* wqt = (int8_t*)d_ws + 4096;              // 2304*256 = 589824 B, [co][k]
    int8_t* xqp = (int8_t*)d_ws + 4096 + 589824;     // 32*58*58*256 = 27,557,888 B

    hipMemsetAsync(maxbits, 0, 4, stream);           // ws poisoned 0xAA -> zero for atomicMax
    k_wmax<<<256, 256, 0, stream>>>(w, maxbits, 3 * 3 * 256 * 256);
    k_wq<<<144, 256, 0, stream>>>(w, maxbits, wqt);
    k_xq<<<6728, 256, 0, stream>>>(x, xqp);          // 32*58*58*16 threads
    dim3 grid(784, 2);                               // 100352/128 x 256/128
    k_conv<<<grid, 256, 0, stream>>>(xqp, wqt, out);
}

// Round 3
// 267.538 us; speedup vs baseline: 1.0575x; 1.0304x over previous
//
#include <hip/hip_runtime.h>
#include <stdint.h>

#define GLOBAL_AS __attribute__((address_space(1)))
#define LDS_AS    __attribute__((address_space(3)))

typedef int v4i  __attribute__((ext_vector_type(4)));
typedef int v16i __attribute__((ext_vector_type(16)));

__device__ __forceinline__ void gload_lds16(const void* g, void* l) {
    __builtin_amdgcn_global_load_lds((GLOBAL_AS uint32_t*)g, (LDS_AS uint32_t*)l, 16, 0, 0);
}

// ---------------- kernel 1: max |tanh(w)| over all 3*3*256*256 weights ----------------
__global__ void k_wmax(const float* __restrict__ w, unsigned* __restrict__ maxbits, int n) {
    int i = blockIdx.x * blockDim.x + threadIdx.x;
    int stride = gridDim.x * blockDim.x;
    float m = 0.f;
    for (; i < n; i += stride) m = fmaxf(m, fabsf(tanhf(w[i])));
#pragma unroll
    for (int off = 32; off > 0; off >>= 1)
        m = fmaxf(m, __shfl_xor(m, off, 64));
    if ((threadIdx.x & 63) == 0) atomicMax(maxbits, __float_as_uint(m));
}

// ---------------- kernel 2: quantize weights -> int8 {-3,-1,1,3}, layout [co][tap*256+ci] ----
__global__ void k_wq(const float* __restrict__ w, const unsigned* __restrict__ maxbits,
                     int8_t* __restrict__ wqt) {
    int t = blockIdx.x * 256 + threadIdx.x;   // 36864 threads
    int co = t & 255;
    int kblk = t >> 8;                        // 0..143, 16 k-values each
    float inv = 0.5f / __uint_as_float(*maxbits);
    int8_t b[16];
#pragma unroll
    for (int i = 0; i < 16; ++i) {
        float tv = tanhf(w[(long)(kblk * 16 + i) * 256 + co]);   // HWIO [k][co]
        int qi = (int)rintf((tv * inv + 0.5f) * 3.0f);           // 0..3, half-even = jnp.round
        b[i] = (int8_t)(2 * qi - 3);                             // {-3,-1,1,3}
    }
    *(int4*)(wqt + (long)co * 2304 + kblk * 16) = *(int4*)b;
}

// ---------------- kernel 3: quantize acts -> int8 {0..3} into zero-padded [32][58][58][256] ---
__global__ void k_xq(const float* __restrict__ x, int8_t* __restrict__ xqp) {
    int t = blockIdx.x * 256 + threadIdx.x;   // 32*58*58*16 threads, 16 bytes each
    int g  = t & 15;
    int p  = t >> 4;
    int xp = p % 58;
    int q  = p / 58;
    int yp = q % 58;
    int n  = q / 58;
    int4 r;
    if (yp == 0 || yp == 57 || xp == 0 || xp == 57) {
        r = make_int4(0, 0, 0, 0);
    } else {
        const float4* px = (const float4*)(x + (((long)((n * 56 + (yp - 1)) * 56 + (xp - 1))) << 8) + g * 16);
        int wds[4];
#pragma unroll
        for (int jj = 0; jj < 4; ++jj) {
            float4 v = px[jj];
            int b0 = (int)rintf(fminf(fmaxf(v.x, 0.f), 1.f) * 3.f);
            int b1 = (int)rintf(fminf(fmaxf(v.y, 0.f), 1.f) * 3.f);
            int b2 = (int)rintf(fminf(fmaxf(v.z, 0.f), 1.f) * 3.f);
            int b3 = (int)rintf(fminf(fmaxf(v.w, 0.f), 1.f) * 3.f);
            wds[jj] = b0 | (b1 << 8) | (b2 << 16) | (b3 << 24);
        }
        r = make_int4(wds[0], wds[1], wds[2], wds[3]);
    }
    *(int4*)(xqp + ((long)t << 4)) = r;
}

// ---------------- kernel 4: pipelined implicit-GEMM conv, i8 MFMA 32x32x32 ------------------
// C[100352][256] = A[M][2304] * B[2304][256]; BM=BN=128, BK=128B, 18 K-iters.
// Double-buffered LDS + raw s_barrier + s_waitcnt vmcnt(8): the 8 prefetch loads for iter
// i+1 stay IN FLIGHT across the barrier (AITER-style), so global latency overlaps compute.
// __syncthreads() is NOT used in the K-loop (it would emit vmcnt(0) and drain the prefetch).
#define BM 128
#define BN 128

__global__ __launch_bounds__(256) void k_conv(const int8_t* __restrict__ xqp,
                                              const int8_t* __restrict__ wqt,
                                              float* __restrict__ out) {
    __shared__ int8_t sA[2][BM * 128];   // 2 x 16 KB
    __shared__ int8_t sB[2][BN * 128];   // 2 x 16 KB

    const int tid    = threadIdx.x;
    const int wv     = tid >> 6;
    const int lane   = tid & 63;
    const int mBase  = blockIdx.x * BM;
    const int coBase = blockIdx.y * BN;

    // staging: instruction (wv, j) covers tile rows rbase..rbase+7, rbase = wv*8 + j*32
    // lane -> row = rbase + (lane>>3), phys chunk p = lane&7, global chunk g = p ^ (row&7)
    const int lr = lane >> 3;
    const int lp = lane & 7;
    const int8_t* aB[4];
    const int8_t* bB[4];
#pragma unroll
    for (int j = 0; j < 4; ++j) {
        int r = wv * 8 + j * 32 + lr;
        int g = lp ^ (r & 7);
        int m = mBase + r;
        int n = m / 3136;
        int rem = m - n * 3136;
        int y = rem / 56;
        int x = rem - y * 56;
        aB[j] = xqp + (((long)((n * 58 + y) * 58 + x)) << 8) + g * 16;
        bB[j] = wqt + (long)(coBase + r) * 2304 + g * 16;
    }

    v16i acc[2][2];
#pragma unroll
    for (int a = 0; a < 2; ++a)
#pragma unroll
        for (int b = 0; b < 2; ++b)
#pragma unroll
            for (int r = 0; r < 16; ++r) acc[a][b][r] = 0;

    const int wm  = (wv & 1) * 64;
    const int wn  = (wv >> 1) * 64;
    const int l31 = lane & 31;
    const int hi  = lane >> 5;

    // fragment row offsets + per-row XOR terms
    const int rA0 = (wm + l31) * 128;       const int axr0 = ((wm + l31) & 7) << 4;
    const int rA1 = (wm + 32 + l31) * 128;  const int axr1 = ((wm + 32 + l31) & 7) << 4;
    const int rB0 = (wn + l31) * 128;       const int bxr0 = ((wn + l31) & 7) << 4;
    const int rB1 = (wn + 32 + l31) * 128;  const int bxr1 = ((wn + 32 + l31) & 7) << 4;

    auto issue = [&](int it, int b) {
        int tap = it >> 1;
        int ky  = tap / 3;
        int kx  = tap - ky * 3;
        int aOff = ((ky * 58 + kx) << 8) + (it & 1) * 128;
        int bOff = tap * 256 + (it & 1) * 128;
#pragma unroll
        for (int j = 0; j < 4; ++j) {
            gload_lds16(aB[j] + aOff, &sA[b][(wv * 8 + j * 32) * 128]);
            gload_lds16(bB[j] + bOff, &sB[b][(wv * 8 + j * 32) * 128]);
        }
    };

    auto compute = [&](int b) {
        const int8_t* pA = sA[b];
        const int8_t* pB = sB[b];
#pragma unroll
        for (int kk = 0; kk < 4; ++kk) {
            const int kc = (kk * 2 + hi) << 4;   // K-chunk byte offset
            v4i a0 = *(const v4i*)(pA + rA0 + (kc ^ axr0));
            v4i a1 = *(const v4i*)(pA + rA1 + (kc ^ axr1));
            v4i b0 = *(const v4i*)(pB + rB0 + (kc ^ bxr0));
            v4i b1 = *(const v4i*)(pB + rB1 + (kc ^ bxr1));
            acc[0][0] = __builtin_amdgcn_mfma_i32_32x32x32_i8(a0, b0, acc[0][0], 0, 0, 0);
            acc[0][1] = __builtin_amdgcn_mfma_i32_32x32x32_i8(a0, b1, acc[0][1], 0, 0, 0);
            acc[1][0] = __builtin_amdgcn_mfma_i32_32x32x32_i8(a1, b0, acc[1][0], 0, 0, 0);
            acc[1][1] = __builtin_amdgcn_mfma_i32_32x32x32_i8(a1, b1, acc[1][1], 0, 0, 0);
        }
    };

    // -------- pipelined K-loop --------
    issue(0, 0);
#pragma unroll 2
    for (int it = 0; it < 17; ++it) {
        issue(it + 1, (it + 1) & 1);                    // prefetch next buffer (8 loads in flight)
        asm volatile("s_waitcnt vmcnt(8)" ::: "memory"); // wait ONLY for current buffer's 8 loads
        __builtin_amdgcn_s_barrier();
        asm volatile("" ::: "memory");
        compute(it & 1);
        asm volatile("" ::: "memory");                   // all waves done reading buf before overwrite
        __builtin_amdgcn_s_barrier();
        asm volatile("" ::: "memory");
    }
    asm volatile("s_waitcnt vmcnt(0)" ::: "memory");     // last iter: drain remaining 8
    __builtin_amdgcn_s_barrier();
    asm volatile("" ::: "memory");
    compute(1);                                          // it=17 -> buf 1

    // epilogue: 32x32 C/D layout col=lane&31, row=(reg&3)+8*(reg>>2)+4*(lane>>5); out = acc/9
    const float s = 1.0f / 9.0f;
#pragma unroll
    for (int mt = 0; mt < 2; ++mt) {
#pragma unroll
        for (int nt = 0; nt < 2; ++nt) {
            const int ocol = coBase + wn + nt * 32 + l31;
#pragma unroll
            for (int reg = 0; reg < 16; ++reg) {
                const int row = (reg & 3) + 8 * (reg >> 2) + 4 * hi;
                const long orow = mBase + wm + mt * 32 + row;
                out[orow * 256 + ocol] = (float)acc[mt][nt][reg] * s;
            }
        }
    }
}

extern "C" void kernel_launch(void* const* d_in, const int* in_sizes, int n_in,
                              void* d_out, int out_size, void* d_ws, size_t ws_size,
                              hipStream_t stream) {
    const float* x = (const float*)d_in[0];   // (32,56,56,256) NHWC fp32
    const float* w = (const float*)d_in[1];   // (3,3,256,256) HWIO fp32
    float* out = (float*)d_out;               // (32,56,56,256) fp32

    unsigned* maxbits = (unsigned*)d_ws;
    int8_t* wqt = (int8_t*)d_ws + 4096;              // 2304*256 = 589824 B, [co][k]
    int8_t* xqp = (int8_t*)d_ws + 4096 + 589824;     // 32*58*58*256 = 27,557,888 B

    hipMemsetAsync(maxbits, 0, 4, stream);           // ws poisoned 0xAA -> zero for atomicMax
    k_wmax<<<256, 256, 0, stream>>>(w, maxbits, 3 * 3 * 256 * 256);
    k_wq<<<144, 256, 0, stream>>>(w, maxbits, wqt);
    k_xq<<<6728, 256, 0, stream>>>(x, xqp);          // 32*58*58*16 threads
    dim3 grid(784, 2);                               // 100352/128 x 256/128
    k_conv<<<grid, 256, 0, stream>>>(xqp, wqt, out);
}